// Round 1
// 624.497 us; speedup vs baseline: 1.0195x; 1.0195x over previous
//
#include <hip/hip_runtime.h>

// EMA over time: out[b,0] = x[b,0]; out[b,t] = 0.99*out[b,t-1] + 0.01*x[b,t]
// Shapes: (B,T,N,D) = (4,128,256,768), fp32 in / fp32 out.
//
// R3: the serial-t version (636 us) ran at 1.27 TB/s = 20% of the 6.3 TB/s the
// harness's own fillBuffer resets achieve -> latency-bound, not BW-bound.
// EMA is a linear recurrence, so parallelize T via chunked scan:
//   - T=128 split into 8 chunks of TC=16 per column (b, r-granule).
//   - Each thread loads its 16 frames up front (16 independent loads in
//     flight vs 1-2 before), computes a zero-init local scan in registers,
//   - chunk-final states exchanged through LDS (8 KiB),
//   - carry applied analytically: out[k] = local[k] + 0.99^(k+1) * carry_in.
// Chunk 0 computes the exact sequential prefix (out[0] = x[0] passthrough).
// Traffic stays at the 805 MB minimum; MLP goes up ~16x per thread and the
// grid grows 768 -> 3072 blocks.

#define EB 4
#define ET 128
#define EN 256
#define ED 768
#define ND4 (EN * ED / 4)   // 49152 float4 granules per (b,t) frame

#define COLS 64             // r-granules per block (one wave = one contiguous 1KB load)
#define CHUNKS 8            // t-chunks per column
#define TC (ET / CHUNKS)    // 16 frames per chunk

__global__ __launch_bounds__(512) void EMAMemory_39891656245789_kernel(
    const float4* __restrict__ in, float4* __restrict__ out) {
    const int tid   = threadIdx.x;
    const int col   = tid & (COLS - 1);   // 0..63
    const int chunk = tid >> 6;           // 0..7

    const unsigned col_g = (unsigned)blockIdx.x * COLS + col;  // 0..196607
    const unsigned b = col_g / ND4;
    const unsigned r = col_g - b * ND4;

    const size_t base = ((size_t)b * ET + (size_t)chunk * TC) * ND4 + r;
    const float4* p = in  + base;
    float4*       q = out + base;

    const float a = 0.99f;
    const float o = 1.0f - 0.99f;

    // ---- load all TC frames of this chunk (16 independent loads in flight) ----
    float4 v[TC];
#pragma unroll
    for (int k = 0; k < TC; ++k) v[k] = p[(size_t)k * ND4];

    // ---- local scan ----
    // chunk 0: v[0] = x[0] (exact passthrough), then the true recurrence.
    // chunk>0: zero-init local scan, l_k = a*l_{k-1} + o*x_k.
    const float w0 = (chunk == 0) ? 1.0f : o;
    v[0].x *= w0; v[0].y *= w0; v[0].z *= w0; v[0].w *= w0;
#pragma unroll
    for (int k = 1; k < TC; ++k) {
        v[k].x = a * v[k - 1].x + o * v[k].x;
        v[k].y = a * v[k - 1].y + o * v[k].y;
        v[k].z = a * v[k - 1].z + o * v[k].z;
        v[k].w = a * v[k - 1].w + o * v[k].w;
    }

    // ---- exchange chunk-final states ----
    __shared__ float4 lds[CHUNKS][COLS];   // 8 KiB
    lds[chunk][col] = v[TC - 1];
    __syncthreads();

    // d16 = 0.99^16 (constant-folded)
    float d16 = 1.0f;
#pragma unroll
    for (int i = 0; i < TC; ++i) d16 *= a;

    // carry_in for this chunk = true memory state at t = chunk*TC - 1.
    // lds[0] holds the exact m_15; lds[c>=1] hold local finals l_15(c):
    //   m_final(c) = l_15(c) + d16 * m_final(c-1)
    float4 cin = make_float4(0.0f, 0.0f, 0.0f, 0.0f);
    if (chunk > 0) {
        cin = lds[0][col];
        for (int c = 1; c < chunk; ++c) {
            float4 t = lds[c][col];
            cin.x = d16 * cin.x + t.x;
            cin.y = d16 * cin.y + t.y;
            cin.z = d16 * cin.z + t.z;
            cin.w = d16 * cin.w + t.w;
        }
    }

    // ---- apply carry and store: out[k] = l_k + a^(k+1) * cin ----
    float pw = a;
#pragma unroll
    for (int k = 0; k < TC; ++k) {
        float4 w = v[k];
        w.x += pw * cin.x;
        w.y += pw * cin.y;
        w.z += pw * cin.z;
        w.w += pw * cin.w;
        q[(size_t)k * ND4] = w;
        pw *= a;
    }
}

extern "C" void kernel_launch(void* const* d_in, const int* in_sizes, int n_in,
                              void* d_out, int out_size, void* d_ws, size_t ws_size,
                              hipStream_t stream) {
    (void)in_sizes; (void)n_in; (void)d_ws; (void)ws_size; (void)out_size;
    const float4* in = (const float4*)d_in[0];
    float4* out = (float4*)d_out;
    // return_per_frame (d_in[1]) is fixed to 1 by setup_inputs.
    const int block = COLS * CHUNKS;                 // 512
    const int grid  = EB * ND4 / COLS;               // 3072 blocks
    hipLaunchKernelGGL(EMAMemory_39891656245789_kernel, dim3(grid), dim3(block), 0,
                       stream, in, out);
}